// Round 16
// baseline (117.051 us; speedup 1.0000x reference)
//
#include <hip/hip_runtime.h>

typedef __attribute__((ext_vector_type(4))) float fx4;
typedef __attribute__((ext_vector_type(16))) float f32x16;
typedef __attribute__((ext_vector_type(8))) short s16x8;
typedef __attribute__((ext_vector_type(2))) unsigned int u32x2;

#define QK_SCALE 0.35355339059327373f   // 1/sqrt(sqrt(64))
#define LOG2E    1.4426950408889634f

__device__ __forceinline__ short f2bf(float f) {
  union { float f; unsigned int u; } v; v.f = f;
  unsigned int r = v.u + 0x7fffu + ((v.u >> 16) & 1u);  // RNE
  return (short)(r >> 16);
}

__device__ __forceinline__ unsigned f2u(float f) {
  union { float f; unsigned u; } v; v.f = f; return v.u;
}
__device__ __forceinline__ float u2f(unsigned u) {
  union { unsigned u; float f; } v; v.u = u; return v.f;
}

// cross-half (lane ^ 32) sum via permlane32_swap builtin (VALU, no LDS).
__device__ __forceinline__ float xhalf_sum(float x) {
  u32x2 r = __builtin_amdgcn_permlane32_swap(f2u(x), f2u(x), false, false);
  return u2f(r[0]) + u2f(r[1]);
}

// XOR swizzle for [rows][64 bf16] LDS tiles (128 B row stride).
__device__ __forceinline__ int swz(int row, int cb) {
  return (row * 128 + cb) ^ ((row & 7) << 4);
}

#define GLL(g, lds) __builtin_amdgcn_global_load_lds( \
    (__attribute__((address_space(1))) void*)(void*)(g), \
    (__attribute__((address_space(3))) void*)(void*)(lds), 16, 0, 0)

// ---------------- fused prep: x->bf16, W transposes ----------------
__global__ __launch_bounds__(256) void prep(
    const float* __restrict__ x, short* __restrict__ x16,
    const float* __restrict__ Wqkv, short* __restrict__ WqkvT,
    const float* __restrict__ Wproj, short* __restrict__ WprojT) {
  const int b = blockIdx.x;
  if (b < 4096) {
    int i = b * 256 + threadIdx.x;
    float4 v = reinterpret_cast<const float4*>(x)[i];
    short4 o;
    o.x = f2bf(v.x); o.y = f2bf(v.y); o.z = f2bf(v.z); o.w = f2bf(v.w);
    reinterpret_cast<short4*>(x16)[i] = o;
    return;
  }
  __shared__ float tile[32][33];
  const float* W; short* WT; int N, bx, by;
  if (b < 7168) { W = Wqkv; WT = WqkvT; N = 3072; int r = b - 4096; bx = r % 96; by = r / 96; }
  else          { W = Wproj; WT = WprojT; N = 1024; int r = b - 7168; bx = r % 32; by = r / 32; }
  const int K = 1024;
  int tx = threadIdx.x & 31, ty = threadIdx.x >> 5;
  int n0 = bx * 32, k0 = by * 32;
#pragma unroll
  for (int i = 0; i < 32; i += 8)
    tile[ty + i][tx] = W[(size_t)(k0 + ty + i) * N + n0 + tx];
  __syncthreads();
#pragma unroll
  for (int i = 0; i < 32; i += 8)
    WT[(size_t)(n0 + ty + i) * K + k0 + tx] = f2bf(tile[tx][ty + i]);
}

// ---------------- qkv GEMM: 256x256 tile, 4-slot LDS ring, counted vmcnt ----------------
// M=4096, N=3072, K=1024. Grid 192 (16 m x 12 n, XCD-bijective), 512 thr = 8 waves
// (2M x 4N), wave-tile 128x64, accT[4][8] (C^T via operand swap).
// BK=32 K-slots in a 4-slot ring (128 KB dynamic LDS): while computing slot s,
// stage slot s+3 -> prefetch depth 3; boundary s_waitcnt vmcnt(8) (never 0 in
// the main loop; tail 8->4->0). Raw s_barrier + sched_barrier(0) fences.
__global__ __launch_bounds__(512, 2) void gemm_qkv(
    const short* __restrict__ A, const short* __restrict__ Bt,
    const float* __restrict__ bias,
    short* __restrict__ Qo, short* __restrict__ Ko, short* __restrict__ Vo) {
  constexpr int K = 1024;
  extern __shared__ __align__(16) char smem[];   // 4 x (A 16K | B 16K) = 128 KB
  const int tid = threadIdx.x;
  const int w = tid >> 6, l = tid & 63;
  const int lr = l & 15, lg = l >> 4;
  const int wm = w >> 2, wn = w & 3;
  const int bid = blockIdx.x;
  const int idx = (bid & 7) * 24 + (bid >> 3);   // bijective: 192 = 8 XCD x 24
  const int m0 = (idx & 15) * 256;
  const int n0 = (idx >> 4) * 256;

  fx4 accT[4][8] = {};   // [n][m]; lane owns row(+lr) x 4 cols(+lg*4)

  // staging: tile rows 256, row = 64 B (BK=32); chunk c: r=c>>2, lch=(c&3)^(r&3)
  auto stageA = [&](int s) {
    char* dst = smem + (s & 3) * 32768;
#pragma unroll
    for (int i = 0; i < 2; ++i) {
      int c = i * 512 + tid, r = c >> 2, lch = (c & 3) ^ (r & 3);
      GLL(A + (size_t)(m0 + r) * K + s * 32 + lch * 8, dst + c * 16);
    }
  };
  auto stageB = [&](int s) {
    char* dst = smem + (s & 3) * 32768 + 16384;
#pragma unroll
    for (int i = 0; i < 2; ++i) {
      int c = i * 512 + tid, r = c >> 2, lch = (c & 3) ^ (r & 3);
      GLL(Bt + (size_t)(n0 + r) * K + s * 32 + lch * 8, dst + c * 16);
    }
  };

  // prologue: stage slots 0..2 (12 loads); wait slot 0 (oldest 4) only
  for (int j = 0; j < 3; ++j) { stageA(j); stageB(j); }
  asm volatile("s_waitcnt vmcnt(8)" ::: "memory");
  __builtin_amdgcn_s_barrier();
  __builtin_amdgcn_sched_barrier(0);

  for (int s = 0; s < 32; ++s) {
    const char* sa = smem + (s & 3) * 32768;
    const char* sb = sa + 16384;
    const bool st = (s + 3 < 32);
    s16x8 bv[4];
#pragma unroll
    for (int mh = 0; mh < 2; ++mh) {
      // interleave: issue next-slot staging + this phase's ds_reads, then barrier+MFMA
      if (mh == 0) { if (st) stageA(s + 3); }
      else         { if (st) stageB(s + 3); }
      s16x8 av[4];
#pragma unroll
      for (int mi = 0; mi < 4; ++mi) {
        int R = wm * 128 + mh * 64 + mi * 16 + lr;
        av[mi] = *reinterpret_cast<const s16x8*>(sa + ((R * 64 + lg * 16) ^ ((R & 3) << 4)));
      }
      if (mh == 0) {
#pragma unroll
        for (int n = 0; n < 4; ++n) {
          int R = wn * 64 + n * 16 + lr;
          bv[n] = *reinterpret_cast<const s16x8*>(sb + ((R * 64 + lg * 16) ^ ((R & 3) << 4)));
        }
      }
      __builtin_amdgcn_s_barrier();
      __builtin_amdgcn_sched_barrier(0);
      __builtin_amdgcn_s_setprio(1);
#pragma unroll
      for (int n = 0; n < 4; ++n)
#pragma unroll
        for (int mi = 0; mi < 4; ++mi)
          accT[n][mh * 4 + mi] = __builtin_amdgcn_mfma_f32_16x16x32_bf16(
              bv[n], av[mi], accT[n][mh * 4 + mi], 0, 0, 0);
      __builtin_amdgcn_s_setprio(0);
      if (mh == 0) {
        __builtin_amdgcn_s_barrier();
        __builtin_amdgcn_sched_barrier(0);
      }
    }
    // slot boundary: wait only the oldest in-flight slot (s+1); keep s+2,s+3 flying
    if (s < 31) {
      if (s <= 28)      asm volatile("s_waitcnt vmcnt(8)" ::: "memory");
      else if (s == 29) asm volatile("s_waitcnt vmcnt(4)" ::: "memory");
      else              asm volatile("s_waitcnt vmcnt(0)" ::: "memory");
      __builtin_amdgcn_s_barrier();
      __builtin_amdgcn_sched_barrier(0);
    }
  }

  // epilogue: scatter Q (scaled, exp2-domain), K (scaled), V^T — as in R15
#pragma unroll
  for (int n = 0; n < 4; ++n) {
    const int col0 = n0 + wn * 64 + n * 16 + lg * 4;
    const float4 bs = *reinterpret_cast<const float4*>(bias + col0);
    const int h = col0 / 192;          // 4-col group never crosses a 64-boundary
    const int rr = col0 - h * 192;
#pragma unroll
    for (int m = 0; m < 8; ++m) {
      int row = m0 + wm * 128 + m * 16 + lr;
      int b = row >> 11, t = row & 2047;
      size_t bh = (size_t)b * 16 + h;
      float v0 = accT[n][m][0] + bs.x, v1 = accT[n][m][1] + bs.y;
      float v2 = accT[n][m][2] + bs.z, v3 = accT[n][m][3] + bs.w;
      if (rr < 64) {
        short4 s4;
        s4.x = f2bf(v0 * (QK_SCALE * LOG2E)); s4.y = f2bf(v1 * (QK_SCALE * LOG2E));
        s4.z = f2bf(v2 * (QK_SCALE * LOG2E)); s4.w = f2bf(v3 * (QK_SCALE * LOG2E));
        *reinterpret_cast<short4*>(Qo + (bh * 2048 + t) * 64 + rr) = s4;
      } else if (rr < 128) {
        short4 s4;
        s4.x = f2bf(v0 * QK_SCALE); s4.y = f2bf(v1 * QK_SCALE);
        s4.z = f2bf(v2 * QK_SCALE); s4.w = f2bf(v3 * QK_SCALE);
        *reinterpret_cast<short4*>(Ko + (bh * 2048 + t) * 64 + (rr - 64)) = s4;
      } else {
        Vo[(bh * 64 + (rr - 128) + 0) * 2048 + t] = f2bf(v0);
        Vo[(bh * 64 + (rr - 128) + 1) * 2048 + t] = f2bf(v1);
        Vo[(bh * 64 + (rr - 128) + 2) * 2048 + t] = f2bf(v2);
        Vo[(bh * 64 + (rr - 128) + 3) * 2048 + t] = f2bf(v3);
      }
    }
  }
}

// ---------------- proj GEMM: 2-phase dbuf (at its structure ceiling) ----------------
template <int BK, int BN>
__global__ __launch_bounds__(BN * 4, 4) void gemm_proj(
    const short* __restrict__ A, const short* __restrict__ Bt,
    const float* __restrict__ bias, float* __restrict__ Cout,
    int M, int N, int K) {
  constexpr int T = BN * 4;
  constexpr int NWC = BN / 32;
  constexpr int CA = 16 * BK / T;
  constexpr int CB = BK / 32;
  __shared__ __align__(16) char sA[2][128 * BK * 2];
  __shared__ __align__(16) char sB[2][BN * BK * 2];
  const int tid = threadIdx.x;
  const int w = tid >> 6, l = tid & 63;
  const int lr = l & 15, lg = l >> 4;
  const int bid = blockIdx.x;
  const int m0 = ((bid & 7) * 4 + ((bid >> 3) & 3)) * 128;
  const int n0 = (bid >> 5) * BN;
  const int wr = (w / NWC) * 64, wc = (w % NWC) * 32;

  fx4 accT[2][4] = {};

  auto stage = [&](int kt, int buf) {
#pragma unroll
    for (int i = 0; i < CA; ++i) {
      int c = i * T + tid;
      int r, lch;
      if (BK == 64) { r = c >> 3; lch = (c & 7) ^ (r & 7); }
      else          { r = c >> 2; lch = (c & 3) ^ (r & 3); }
      GLL(A + (size_t)(m0 + r) * K + kt + lch * 8, sA[buf] + c * 16);
    }
#pragma unroll
    for (int i = 0; i < CB; ++i) {
      int c = i * T + tid;
      int r, lch;
      if (BK == 64) { r = c >> 3; lch = (c & 7) ^ (r & 7); }
      else          { r = c >> 2; lch = (c & 3) ^ (r & 3); }
      GLL(Bt + (size_t)(n0 + r) * K + kt + lch * 8, sB[buf] + c * 16);
    }
  };
  auto roff = [&](int R, int kk) {
    return (BK == 64) ? ((R * 128 + kk * 64 + lg * 16) ^ ((R & 7) << 4))
                      : ((R * 64 + lg * 16) ^ ((R & 3) << 4));
  };

  stage(0, 0);
  __syncthreads();

  const int NIT = K / BK;
  int cur = 0;
  for (int it = 0; it < NIT; ++it) {
    if (it + 1 < NIT) stage((it + 1) * BK, cur ^ 1);
#pragma unroll
    for (int kk = 0; kk < (BK == 64 ? 2 : 1); ++kk) {
      s16x8 av[4], bv[2];
#pragma unroll
      for (int m = 0; m < 4; ++m)
        av[m] = *reinterpret_cast<const s16x8*>(sA[cur] + roff(wr + m * 16 + lr, kk));
#pragma unroll
      for (int n = 0; n < 2; ++n)
        bv[n] = *reinterpret_cast<const s16x8*>(sB[cur] + roff(wc + n * 16 + lr, kk));
#pragma unroll
      for (int n = 0; n < 2; ++n)
#pragma unroll
        for (int m = 0; m < 4; ++m)
          accT[n][m] = __builtin_amdgcn_mfma_f32_16x16x32_bf16(bv[n], av[m], accT[n][m], 0, 0, 0);
    }
    __syncthreads();
    cur ^= 1;
  }

#pragma unroll
  for (int n = 0; n < 2; ++n) {
    const int col0 = n0 + wc + n * 16 + lg * 4;
    const float4 bs = *reinterpret_cast<const float4*>(bias + col0);
#pragma unroll
    for (int m = 0; m < 4; ++m) {
      int row = m0 + wr + m * 16 + lr;
      float4 v;
      v.x = accT[n][m][0] + bs.x; v.y = accT[n][m][1] + bs.y;
      v.z = accT[n][m][2] + bs.z; v.w = accT[n][m][3] + bs.w;
      *reinterpret_cast<float4*>(Cout + (size_t)row * N + col0) = v;
    }
  }
}

// ---------------- flash attention: IN-BLOCK 2-way split-KV + LDS merge (R15) ----------------
__global__ __launch_bounds__(512, 4) void attn_fwd(
    const short* __restrict__ Q, const short* __restrict__ Kc,
    const short* __restrict__ VT, short* __restrict__ Y) {
  __shared__ __align__(16) char smem[65536];  // [K: 2half x 2buf x 8K][V: same]
  const int tid = threadIdx.x;
  const int w = tid >> 6;
  const int wq = w & 3;
  const int half = w >> 2;
  const int t8 = tid & 255;
  const int l = tid & 63;
  const int l31 = l & 31, hi = l >> 5;
  const int bid = blockIdx.x;
  const int bh = (bid & 7) * 4 + ((bid >> 3) & 3);
  const int qt = bid >> 5;
  const int q0 = qt * 128 + wq * 32;
  const int sbase = half * 1024;

  char* kbase = smem + half * 16384;
  char* vbase = smem + 32768 + half * 16384;

  s16x8 qf[4];
  const short* qp = Q + ((size_t)bh * 2048 + q0 + l31) * 64 + hi * 8;
#pragma unroll
  for (int ks = 0; ks < 4; ++ks)
    qf[ks] = *reinterpret_cast<const s16x8*>(qp + ks * 16);

  float lsum = 0.f;
  f32x16 o0 = {}, o1 = {};

#pragma unroll
  for (int i = 0; i < 2; ++i) {
    int c = i * 256 + t8, r = c >> 3, pch = c & 7, lch = pch ^ (r & 7);
    GLL(Kc + ((size_t)bh * 2048 + sbase + r) * 64 + lch * 8, kbase + c * 16);
    GLL(VT + ((size_t)bh * 64 + r) * 2048 + sbase + lch * 8, vbase + c * 16);
  }
  __syncthreads();

  for (int sb = 0; sb < 16; ++sb) {
    const int s0 = sbase + sb * 64;
    if (sb < 15) {
      char* kn = kbase + ((sb + 1) & 1) * 8192;
      char* vn = vbase + ((sb + 1) & 1) * 8192;
#pragma unroll
      for (int i = 0; i < 2; ++i) {
        int c = i * 256 + t8, r = c >> 3, pch = c & 7, lch = pch ^ (r & 7);
        GLL(Kc + ((size_t)bh * 2048 + s0 + 64 + r) * 64 + lch * 8, kn + c * 16);
        GLL(VT + ((size_t)bh * 64 + r) * 2048 + s0 + 64 + lch * 8, vn + c * 16);
      }
    }
    const char* kb = kbase + (sb & 1) * 8192;
    const char* vb = vbase + (sb & 1) * 8192;

    f32x16 p0 = {}, p1 = {};
    __builtin_amdgcn_s_setprio(1);
#pragma unroll
    for (int ks = 0; ks < 4; ++ks) {
      int off = swz(l31, ks * 32 + hi * 16);
      s16x8 ka0 = *reinterpret_cast<const s16x8*>(kb + off);
      s16x8 ka1 = *reinterpret_cast<const s16x8*>(kb + off + 4096);
      p0 = __builtin_amdgcn_mfma_f32_32x32x16_bf16(ka0, qf[ks], p0, 0, 0, 0);
      p1 = __builtin_amdgcn_mfma_f32_32x32x16_bf16(ka1, qf[ks], p1, 0, 0, 0);
    }
    __builtin_amdgcn_s_setprio(0);

#pragma unroll
    for (int i = 0; i < 16; ++i) {
      p0[i] = __builtin_amdgcn_exp2f(p0[i]);
      p1[i] = __builtin_amdgcn_exp2f(p1[i]);
    }
    float s8[8];
#pragma unroll
    for (int i = 0; i < 8; ++i)
      s8[i] = (p0[2 * i] + p0[2 * i + 1]) + (p1[2 * i] + p1[2 * i + 1]);
    lsum += ((s8[0] + s8[1]) + (s8[2] + s8[3])) + ((s8[4] + s8[5]) + (s8[6] + s8[7]));

    int wd[16];
#pragma unroll
    for (int i = 0; i < 8; ++i) {
      asm("v_cvt_pk_bf16_f32 %0, %1, %2" : "=v"(wd[i]) : "v"(p0[2 * i]), "v"(p0[2 * i + 1]));
      asm("v_cvt_pk_bf16_f32 %0, %1, %2" : "=v"(wd[8 + i]) : "v"(p1[2 * i]), "v"(p1[2 * i + 1]));
    }

    __builtin_amdgcn_s_setprio(1);
#pragma unroll
    for (int t = 0; t < 4; ++t) {
      u32x2 s02 = __builtin_amdgcn_permlane32_swap(
          (unsigned)wd[4 * t], (unsigned)wd[4 * t + 2], false, false);
      u32x2 s13 = __builtin_amdgcn_permlane32_swap(
          (unsigned)wd[4 * t + 1], (unsigned)wd[4 * t + 3], false, false);
      union { unsigned i4[4]; s16x8 v; } fr;
      fr.i4[0] = s02[0]; fr.i4[1] = s13[0]; fr.i4[2] = s02[1]; fr.i4[3] = s13[1];
      int off = swz(l31, t * 32 + hi * 16);
      s16x8 v0 = *reinterpret_cast<const s16x8*>(vb + off);
      s16x8 v1 = *reinterpret_cast<const s16x8*>(vb + off + 4096);
      o0 = __builtin_amdgcn_mfma_f32_32x32x16_bf16(v0, fr.v, o0, 0, 0, 0);
      o1 = __builtin_amdgcn_mfma_f32_32x32x16_bf16(v1, fr.v, o1, 0, 0, 0);
    }
    __builtin_amdgcn_s_setprio(0);
    __syncthreads();
  }

  float lt = xhalf_sum(lsum);
  float* scr = (float*)smem;
  float* slsum = (float*)(smem + 32768);
  if (half == 1) {
    float* op = scr + wq * 2048;
#pragma unroll
    for (int gq = 0; gq < 4; ++gq)
#pragma unroll
      for (int j = 0; j < 4; ++j) {
        op[(hi * 4 + 8 * gq + j) * 32 + l31] = o0[4 * gq + j];
        op[(32 + hi * 4 + 8 * gq + j) * 32 + l31] = o1[4 * gq + j];
      }
    if (hi == 0) slsum[wq * 32 + l31] = lt;
  }
  __syncthreads();
  if (half == 0) {
    const int b = bh >> 4, h = bh & 15;
    float inv = 1.f / (lt + slsum[wq * 32 + l31]);
    const float* op = scr + wq * 2048;
    short* yp = Y + ((size_t)b * 2048 + q0 + l31) * 1024 + h * 64 + hi * 4;
#pragma unroll
    for (int gq = 0; gq < 4; ++gq) {
      short4 s4;
      s4.x = f2bf((o0[4 * gq + 0] + op[(hi * 4 + 8 * gq + 0) * 32 + l31]) * inv);
      s4.y = f2bf((o0[4 * gq + 1] + op[(hi * 4 + 8 * gq + 1) * 32 + l31]) * inv);
      s4.z = f2bf((o0[4 * gq + 2] + op[(hi * 4 + 8 * gq + 2) * 32 + l31]) * inv);
      s4.w = f2bf((o0[4 * gq + 3] + op[(hi * 4 + 8 * gq + 3) * 32 + l31]) * inv);
      *reinterpret_cast<short4*>(yp + 8 * gq) = s4;
      s4.x = f2bf((o1[4 * gq + 0] + op[(32 + hi * 4 + 8 * gq + 0) * 32 + l31]) * inv);
      s4.y = f2bf((o1[4 * gq + 1] + op[(32 + hi * 4 + 8 * gq + 1) * 32 + l31]) * inv);
      s4.z = f2bf((o1[4 * gq + 2] + op[(32 + hi * 4 + 8 * gq + 2) * 32 + l31]) * inv);
      s4.w = f2bf((o1[4 * gq + 3] + op[(32 + hi * 4 + 8 * gq + 3) * 32 + l31]) * inv);
      *reinterpret_cast<short4*>(yp + 32 + 8 * gq) = s4;
    }
  }
}

// ---------------- launcher ----------------
extern "C" void kernel_launch(void* const* d_in, const int* in_sizes, int n_in,
                              void* d_out, int out_size, void* d_ws, size_t ws_size,
                              hipStream_t stream) {
  const float* x     = (const float*)d_in[0];
  const float* Wqkv  = (const float*)d_in[1];
  const float* bqkv  = (const float*)d_in[2];
  const float* Wproj = (const float*)d_in[3];
  const float* bproj = (const float*)d_in[4];
  float* out = (float*)d_out;

  char* ws = (char*)d_ws;
  const size_t MB = 1024 * 1024;
  short* x16    = (short*)(ws);             // 8 MB (reused as Y16 after attn)
  short* WqkvT  = (short*)(ws + 8 * MB);    // 6 MB
  short* WprojT = (short*)(ws + 14 * MB);   // 2 MB
  short* Q16    = (short*)(ws + 16 * MB);   // 8 MB  [bh][t][64]  (scaled by s*log2e)
  short* K16    = (short*)(ws + 24 * MB);   // 8 MB  [bh][t][64]  (scaled by s)
  short* VT16   = (short*)(ws + 32 * MB);   // 8 MB  [bh][64][t]
  short* Y16    = x16;                      // 8 MB  [b*t][1024]

  hipFuncSetAttribute(reinterpret_cast<const void*>(gemm_qkv),
                      hipFuncAttributeMaxDynamicSharedMemorySize, 131072);

  prep<<<8192, 256, 0, stream>>>(x, x16, Wqkv, WqkvT, Wproj, WprojT);
  gemm_qkv<<<192, 512, 131072, stream>>>(x16, WqkvT, bqkv, Q16, K16, VT16);
  attn_fwd<<<512, 512, 0, stream>>>(Q16, K16, VT16, Y16);
  gemm_proj<64, 64><<<512, 256, 0, stream>>>(Y16, WprojT, bproj, out, 4096, 1024, 1024);
}

// Round 17
// 109.902 us; speedup vs baseline: 1.0650x; 1.0650x over previous
//
#include <hip/hip_runtime.h>

typedef __attribute__((ext_vector_type(4))) float fx4;
typedef __attribute__((ext_vector_type(16))) float f32x16;
typedef __attribute__((ext_vector_type(8))) short s16x8;
typedef __attribute__((ext_vector_type(2))) unsigned int u32x2;

#define QK_SCALE 0.35355339059327373f   // 1/sqrt(sqrt(64))
#define LOG2E    1.4426950408889634f

__device__ __forceinline__ short f2bf(float f) {
  union { float f; unsigned int u; } v; v.f = f;
  unsigned int r = v.u + 0x7fffu + ((v.u >> 16) & 1u);  // RNE
  return (short)(r >> 16);
}

__device__ __forceinline__ unsigned f2u(float f) {
  union { float f; unsigned u; } v; v.f = f; return v.u;
}
__device__ __forceinline__ float u2f(unsigned u) {
  union { unsigned u; float f; } v; v.u = u; return v.f;
}

// cross-half (lane ^ 32) sum via permlane32_swap builtin (VALU, no LDS).
__device__ __forceinline__ float xhalf_sum(float x) {
  u32x2 r = __builtin_amdgcn_permlane32_swap(f2u(x), f2u(x), false, false);
  return u2f(r[0]) + u2f(r[1]);
}

// XOR swizzle for [rows][64 bf16] LDS tiles (128 B row stride).
__device__ __forceinline__ int swz(int row, int cb) {
  return (row * 128 + cb) ^ ((row & 7) << 4);
}

#define GLL(g, lds) __builtin_amdgcn_global_load_lds( \
    (__attribute__((address_space(1))) void*)(void*)(g), \
    (__attribute__((address_space(3))) void*)(void*)(lds), 16, 0, 0)

// ---------------- fused prep: x->bf16, W transposes ----------------
__global__ __launch_bounds__(256) void prep(
    const float* __restrict__ x, short* __restrict__ x16,
    const float* __restrict__ Wqkv, short* __restrict__ WqkvT,
    const float* __restrict__ Wproj, short* __restrict__ WprojT) {
  const int b = blockIdx.x;
  if (b < 4096) {
    int i = b * 256 + threadIdx.x;
    float4 v = reinterpret_cast<const float4*>(x)[i];
    short4 o;
    o.x = f2bf(v.x); o.y = f2bf(v.y); o.z = f2bf(v.z); o.w = f2bf(v.w);
    reinterpret_cast<short4*>(x16)[i] = o;
    return;
  }
  __shared__ float tile[32][33];
  const float* W; short* WT; int N, bx, by;
  if (b < 7168) { W = Wqkv; WT = WqkvT; N = 3072; int r = b - 4096; bx = r % 96; by = r / 96; }
  else          { W = Wproj; WT = WprojT; N = 1024; int r = b - 7168; bx = r % 32; by = r / 32; }
  const int K = 1024;
  int tx = threadIdx.x & 31, ty = threadIdx.x >> 5;
  int n0 = bx * 32, k0 = by * 32;
#pragma unroll
  for (int i = 0; i < 32; i += 8)
    tile[ty + i][tx] = W[(size_t)(k0 + ty + i) * N + n0 + tx];
  __syncthreads();
#pragma unroll
  for (int i = 0; i < 32; i += 8)
    WT[(size_t)(n0 + ty + i) * K + k0 + tx] = f2bf(tile[tx][ty + i]);
}

// ---------------- GEMM: C[M][N] = A[M][K] @ Bt[N][K]^T (+bias) ----------------
// BM=128 fixed; templated BK (64: 128B rows; 32: 64B rows) and BN (128 or 64).
// Wave-tile 64x32 (accT[2][4]); threads = BN*4. Double-buffered LDS,
// C^T accumulation (operand swap) -> vectorized epilogue.
template <int MODE, int BK, int BN>
__global__ __launch_bounds__(BN * 4, 4) void gemm_bf16(
    const short* __restrict__ A, const short* __restrict__ Bt,
    const float* __restrict__ bias, float* __restrict__ Cout,
    short* __restrict__ Qo, short* __restrict__ Ko, short* __restrict__ Vo,
    int M, int N, int K) {
  constexpr int T = BN * 4;           // threads
  constexpr int NWC = BN / 32;        // wave columns
  constexpr int CA = 16 * BK / T;     // A chunks per thread
  constexpr int CB = BK / 32;         // B chunks per thread
  __shared__ __align__(16) char sA[2][128 * BK * 2];
  __shared__ __align__(16) char sB[2][BN * BK * 2];
  const int tid = threadIdx.x;
  const int w = tid >> 6, l = tid & 63;
  const int lr = l & 15, lg = l >> 4;
  const int bid = blockIdx.x;
  const int m0 = ((bid & 7) * 4 + ((bid >> 3) & 3)) * 128;  // XCD-grouped (32 m-tiles)
  const int n0 = (bid >> 5) * BN;
  const int wr = (w / NWC) * 64, wc = (w % NWC) * 32;

  fx4 accT[2][4] = {};

  auto stage = [&](int kt, int buf) {
#pragma unroll
    for (int i = 0; i < CA; ++i) {
      int c = i * T + tid;
      int r, lch;
      if (BK == 64) { r = c >> 3; lch = (c & 7) ^ (r & 7); }
      else          { r = c >> 2; lch = (c & 3) ^ (r & 3); }
      GLL(A + (size_t)(m0 + r) * K + kt + lch * 8, sA[buf] + c * 16);
    }
#pragma unroll
    for (int i = 0; i < CB; ++i) {
      int c = i * T + tid;
      int r, lch;
      if (BK == 64) { r = c >> 3; lch = (c & 7) ^ (r & 7); }
      else          { r = c >> 2; lch = (c & 3) ^ (r & 3); }
      GLL(Bt + (size_t)(n0 + r) * K + kt + lch * 8, sB[buf] + c * 16);
    }
  };
  auto roff = [&](int R, int kk) {
    return (BK == 64) ? ((R * 128 + kk * 64 + lg * 16) ^ ((R & 7) << 4))
                      : ((R * 64 + lg * 16) ^ ((R & 3) << 4));
  };

  stage(0, 0);
  __syncthreads();

  const int NIT = K / BK;
  int cur = 0;
  for (int it = 0; it < NIT; ++it) {
    if (it + 1 < NIT) stage((it + 1) * BK, cur ^ 1);
#pragma unroll
    for (int kk = 0; kk < (BK == 64 ? 2 : 1); ++kk) {
      s16x8 av[4], bv[2];
#pragma unroll
      for (int m = 0; m < 4; ++m)
        av[m] = *reinterpret_cast<const s16x8*>(sA[cur] + roff(wr + m * 16 + lr, kk));
#pragma unroll
      for (int n = 0; n < 2; ++n)
        bv[n] = *reinterpret_cast<const s16x8*>(sB[cur] + roff(wc + n * 16 + lr, kk));
#pragma unroll
      for (int n = 0; n < 2; ++n)
#pragma unroll
        for (int m = 0; m < 4; ++m)
          accT[n][m] = __builtin_amdgcn_mfma_f32_16x16x32_bf16(bv[n], av[m], accT[n][m], 0, 0, 0);
    }
    __syncthreads();
    cur ^= 1;
  }

  // epilogue: lane owns row = m0+wr+m*16+lr, cols col0..col0+3
#pragma unroll
  for (int n = 0; n < 2; ++n) {
    const int col0 = n0 + wc + n * 16 + lg * 4;
    const float4 bs = *reinterpret_cast<const float4*>(bias + col0);
    if (MODE == 1) {
#pragma unroll
      for (int m = 0; m < 4; ++m) {
        int row = m0 + wr + m * 16 + lr;
        float4 v;
        v.x = accT[n][m][0] + bs.x; v.y = accT[n][m][1] + bs.y;
        v.z = accT[n][m][2] + bs.z; v.w = accT[n][m][3] + bs.w;
        *reinterpret_cast<float4*>(Cout + (size_t)row * N + col0) = v;
      }
    } else {
      const int h = col0 / 192;          // 4-col group never crosses a 64-boundary
      const int rr = col0 - h * 192;
#pragma unroll
      for (int m = 0; m < 4; ++m) {
        int row = m0 + wr + m * 16 + lr;
        int b = row >> 11, t = row & 2047;
        size_t bh = (size_t)b * 16 + h;
        float v0 = accT[n][m][0] + bs.x, v1 = accT[n][m][1] + bs.y;
        float v2 = accT[n][m][2] + bs.z, v3 = accT[n][m][3] + bs.w;
        if (rr < 64) {
          short4 s4;
          s4.x = f2bf(v0 * (QK_SCALE * LOG2E)); s4.y = f2bf(v1 * (QK_SCALE * LOG2E));
          s4.z = f2bf(v2 * (QK_SCALE * LOG2E)); s4.w = f2bf(v3 * (QK_SCALE * LOG2E));
          *reinterpret_cast<short4*>(Qo + (bh * 2048 + t) * 64 + rr) = s4;
        } else if (rr < 128) {
          short4 s4;
          s4.x = f2bf(v0 * QK_SCALE); s4.y = f2bf(v1 * QK_SCALE);
          s4.z = f2bf(v2 * QK_SCALE); s4.w = f2bf(v3 * QK_SCALE);
          *reinterpret_cast<short4*>(Ko + (bh * 2048 + t) * 64 + (rr - 64)) = s4;
        } else {
          Vo[(bh * 64 + (rr - 128) + 0) * 2048 + t] = f2bf(v0);
          Vo[(bh * 64 + (rr - 128) + 1) * 2048 + t] = f2bf(v1);
          Vo[(bh * 64 + (rr - 128) + 2) * 2048 + t] = f2bf(v2);
          Vo[(bh * 64 + (rr - 128) + 3) * 2048 + t] = f2bf(v3);
        }
      }
    }
  }
}

// ---------------- flash attention: IN-BLOCK 2-way split-KV + LDS merge ----------------
// grid 512 = 32 bh x 16 q-tiles(128 rows), XCD-grouped by bh. 512 threads = 8 waves:
// waves 0-3 process KV half 0 (q-subtiles 0-3), waves 4-7 half 1 (same q-subtiles).
// Epilogue: group-1 waves dump fp32 O + lsum to LDS (overlaps dead staging bufs);
// group-0 waves combine (O0+O1)/(l0+l1) and write Y directly.
__global__ __launch_bounds__(512, 4) void attn_fwd(
    const short* __restrict__ Q, const short* __restrict__ Kc,
    const short* __restrict__ VT, short* __restrict__ Y) {
  __shared__ __align__(16) char smem[65536];  // [K: 2half x 2buf x 8K][V: same]
  const int tid = threadIdx.x;
  const int w = tid >> 6;
  const int wq = w & 3;
  const int half = w >> 2;
  const int t8 = tid & 255;
  const int l = tid & 63;
  const int l31 = l & 31, hi = l >> 5;
  const int bid = blockIdx.x;
  const int bh = (bid & 7) * 4 + ((bid >> 3) & 3);
  const int qt = bid >> 5;
  const int q0 = qt * 128 + wq * 32;
  const int sbase = half * 1024;

  char* kbase = smem + half * 16384;
  char* vbase = smem + 32768 + half * 16384;

  s16x8 qf[4];
  const short* qp = Q + ((size_t)bh * 2048 + q0 + l31) * 64 + hi * 8;
#pragma unroll
  for (int ks = 0; ks < 4; ++ks)
    qf[ks] = *reinterpret_cast<const s16x8*>(qp + ks * 16);

  float lsum = 0.f;
  f32x16 o0 = {}, o1 = {};

#pragma unroll
  for (int i = 0; i < 2; ++i) {
    int c = i * 256 + t8, r = c >> 3, pch = c & 7, lch = pch ^ (r & 7);
    GLL(Kc + ((size_t)bh * 2048 + sbase + r) * 64 + lch * 8, kbase + c * 16);
    GLL(VT + ((size_t)bh * 64 + r) * 2048 + sbase + lch * 8, vbase + c * 16);
  }
  __syncthreads();

  for (int sb = 0; sb < 16; ++sb) {
    const int s0 = sbase + sb * 64;
    if (sb < 15) {
      char* kn = kbase + ((sb + 1) & 1) * 8192;
      char* vn = vbase + ((sb + 1) & 1) * 8192;
#pragma unroll
      for (int i = 0; i < 2; ++i) {
        int c = i * 256 + t8, r = c >> 3, pch = c & 7, lch = pch ^ (r & 7);
        GLL(Kc + ((size_t)bh * 2048 + s0 + 64 + r) * 64 + lch * 8, kn + c * 16);
        GLL(VT + ((size_t)bh * 64 + r) * 2048 + s0 + 64 + lch * 8, vn + c * 16);
      }
    }
    const char* kb = kbase + (sb & 1) * 8192;
    const char* vb = vbase + (sb & 1) * 8192;

    f32x16 p0 = {}, p1 = {};
    __builtin_amdgcn_s_setprio(1);
#pragma unroll
    for (int ks = 0; ks < 4; ++ks) {
      int off = swz(l31, ks * 32 + hi * 16);
      s16x8 ka0 = *reinterpret_cast<const s16x8*>(kb + off);
      s16x8 ka1 = *reinterpret_cast<const s16x8*>(kb + off + 4096);
      p0 = __builtin_amdgcn_mfma_f32_32x32x16_bf16(ka0, qf[ks], p0, 0, 0, 0);
      p1 = __builtin_amdgcn_mfma_f32_32x32x16_bf16(ka1, qf[ks], p1, 0, 0, 0);
    }
    __builtin_amdgcn_s_setprio(0);

#pragma unroll
    for (int i = 0; i < 16; ++i) {
      p0[i] = __builtin_amdgcn_exp2f(p0[i]);
      p1[i] = __builtin_amdgcn_exp2f(p1[i]);
    }
    float s8[8];
#pragma unroll
    for (int i = 0; i < 8; ++i)
      s8[i] = (p0[2 * i] + p0[2 * i + 1]) + (p1[2 * i] + p1[2 * i + 1]);
    lsum += ((s8[0] + s8[1]) + (s8[2] + s8[3])) + ((s8[4] + s8[5]) + (s8[6] + s8[7]));

    int wd[16];
#pragma unroll
    for (int i = 0; i < 8; ++i) {
      asm("v_cvt_pk_bf16_f32 %0, %1, %2" : "=v"(wd[i]) : "v"(p0[2 * i]), "v"(p0[2 * i + 1]));
      asm("v_cvt_pk_bf16_f32 %0, %1, %2" : "=v"(wd[8 + i]) : "v"(p1[2 * i]), "v"(p1[2 * i + 1]));
    }

    __builtin_amdgcn_s_setprio(1);
#pragma unroll
    for (int t = 0; t < 4; ++t) {
      u32x2 s02 = __builtin_amdgcn_permlane32_swap(
          (unsigned)wd[4 * t], (unsigned)wd[4 * t + 2], false, false);
      u32x2 s13 = __builtin_amdgcn_permlane32_swap(
          (unsigned)wd[4 * t + 1], (unsigned)wd[4 * t + 3], false, false);
      union { unsigned i4[4]; s16x8 v; } fr;
      fr.i4[0] = s02[0]; fr.i4[1] = s13[0]; fr.i4[2] = s02[1]; fr.i4[3] = s13[1];
      int off = swz(l31, t * 32 + hi * 16);
      s16x8 v0 = *reinterpret_cast<const s16x8*>(vb + off);
      s16x8 v1 = *reinterpret_cast<const s16x8*>(vb + off + 4096);
      o0 = __builtin_amdgcn_mfma_f32_32x32x16_bf16(v0, fr.v, o0, 0, 0, 0);
      o1 = __builtin_amdgcn_mfma_f32_32x32x16_bf16(v1, fr.v, o1, 0, 0, 0);
    }
    __builtin_amdgcn_s_setprio(0);
    __syncthreads();
  }

  float lt = xhalf_sum(lsum);
  float* scr = (float*)smem;
  float* slsum = (float*)(smem + 32768);
  if (half == 1) {
    float* op = scr + wq * 2048;
#pragma unroll
    for (int gq = 0; gq < 4; ++gq)
#pragma unroll
      for (int j = 0; j < 4; ++j) {
        op[(hi * 4 + 8 * gq + j) * 32 + l31] = o0[4 * gq + j];
        op[(32 + hi * 4 + 8 * gq + j) * 32 + l31] = o1[4 * gq + j];
      }
    if (hi == 0) slsum[wq * 32 + l31] = lt;
  }
  __syncthreads();
  if (half == 0) {
    const int b = bh >> 4, h = bh & 15;
    float inv = 1.f / (lt + slsum[wq * 32 + l31]);
    const float* op = scr + wq * 2048;
    short* yp = Y + ((size_t)b * 2048 + q0 + l31) * 1024 + h * 64 + hi * 4;
#pragma unroll
    for (int gq = 0; gq < 4; ++gq) {
      short4 s4;
      s4.x = f2bf((o0[4 * gq + 0] + op[(hi * 4 + 8 * gq + 0) * 32 + l31]) * inv);
      s4.y = f2bf((o0[4 * gq + 1] + op[(hi * 4 + 8 * gq + 1) * 32 + l31]) * inv);
      s4.z = f2bf((o0[4 * gq + 2] + op[(hi * 4 + 8 * gq + 2) * 32 + l31]) * inv);
      s4.w = f2bf((o0[4 * gq + 3] + op[(hi * 4 + 8 * gq + 3) * 32 + l31]) * inv);
      *reinterpret_cast<short4*>(yp + 8 * gq) = s4;
      s4.x = f2bf((o1[4 * gq + 0] + op[(32 + hi * 4 + 8 * gq + 0) * 32 + l31]) * inv);
      s4.y = f2bf((o1[4 * gq + 1] + op[(32 + hi * 4 + 8 * gq + 1) * 32 + l31]) * inv);
      s4.z = f2bf((o1[4 * gq + 2] + op[(32 + hi * 4 + 8 * gq + 2) * 32 + l31]) * inv);
      s4.w = f2bf((o1[4 * gq + 3] + op[(32 + hi * 4 + 8 * gq + 3) * 32 + l31]) * inv);
      *reinterpret_cast<short4*>(yp + 32 + 8 * gq) = s4;
    }
  }
}

// ---------------- launcher ----------------
extern "C" void kernel_launch(void* const* d_in, const int* in_sizes, int n_in,
                              void* d_out, int out_size, void* d_ws, size_t ws_size,
                              hipStream_t stream) {
  const float* x     = (const float*)d_in[0];
  const float* Wqkv  = (const float*)d_in[1];
  const float* bqkv  = (const float*)d_in[2];
  const float* Wproj = (const float*)d_in[3];
  const float* bproj = (const float*)d_in[4];
  float* out = (float*)d_out;

  char* ws = (char*)d_ws;
  const size_t MB = 1024 * 1024;
  short* x16    = (short*)(ws);             // 8 MB (reused as Y16 after attn)
  short* WqkvT  = (short*)(ws + 8 * MB);    // 6 MB
  short* WprojT = (short*)(ws + 14 * MB);   // 2 MB
  short* Q16    = (short*)(ws + 16 * MB);   // 8 MB  [bh][t][64]  (scaled by s*log2e)
  short* K16    = (short*)(ws + 24 * MB);   // 8 MB  [bh][t][64]  (scaled by s)
  short* VT16   = (short*)(ws + 32 * MB);   // 8 MB  [bh][64][t]
  short* Y16    = x16;                      // 8 MB  [b*t][1024]

  prep<<<8192, 256, 0, stream>>>(x, x16, Wqkv, WqkvT, Wproj, WprojT);
  gemm_bf16<0, 32, 128><<<768, 512, 0, stream>>>(x16, WqkvT, bqkv, nullptr,
                                                 Q16, K16, VT16, 4096, 3072, 1024);
  attn_fwd<<<512, 512, 0, stream>>>(Q16, K16, VT16, Y16);
  gemm_bf16<1, 64, 64><<<512, 256, 0, stream>>>(Y16, WprojT, bproj, out,
                                                nullptr, nullptr, nullptr, 4096, 1024, 1024);
}